// Round 14
// baseline (152.045 us; speedup 1.0000x reference)
//
#include <hip/hip_runtime.h>
#include <hip/hip_bf16.h>

// Problem: B=2, S=2048, D=768, H=12, HD=64. fp32 in/out, bf16 MFMA inside.
// r35 = r34 (149.3us champion) + GEMM memory-side upgrades:
// (1) XCD remap on BOTH GEMMs (r31 mechanism): old n-fastest linearization
//     spread the 24 blocks sharing an A row-panel over all 8 XCDs (each XCD
//     re-fetches every panel). Now xcd=id&7 owns MPX whole m-panels ->
//     A+B working set ~4MB (G1) / ~2MB (G2) = L2-resident staging.
// (2) GEMM2 rebuilt as r34's exact 3-buffer counted-vmcnt pipeline (BK=64,
//     4 loads/thread/tile, vmcnt(4)): LDS 16->48KB but grid already caps at
//     3 blk/CU -> zero occupancy cost, full-iteration staging slack vs the
//     old per-iter vmcnt(0) drain. GEMM1 pipeline deferred (would cost
//     3->2 blk/CU; measure swizzle-only first).
// Win ledger: r4 LDS staging+dbuf, r5 xor-swizzle, r18 GEMM1 128x96,
// r22 swapped-QK^T in-register P, r24 glds16 pre-swizzled staging +
// l-on-MFMA, r30 GEMM BK=64 swizzle, r31 XCD remap + repack fold,
// r32 unsplit attn, r33 raw v_exp_f32, r34 attn 3-buf counted vmcnt
// (47.8->45.2).
// Failure ledger (do not revisit): r7 mfma16, r8 wave-split, r11 32x32 MFMA,
// r12 attn BK=64, r9/r13/r14 math micro-opts, r16 GEMM1 64x128, r20 GEMM2
// dbuf-at-BK32, r23 2-wave/32q blocks, r25 V-direct-global mid-iter, r27
// V-reg prefetch post-PV, r28 gemm2-fused combine, r29 cross-block combine
// (tripwire FAIL), r30 attn setprio, r26/r31 split-k (combine tax).
#define B_ 2
#define S_ 2048
#define D_ 768
#define H_ 12
#define HD_ 64
#define EXP2C_ 0.1803368801111244f  // SCALE * log2(e), folded into Q

typedef __attribute__((ext_vector_type(8))) short bf16x8;
typedef __attribute__((ext_vector_type(8))) unsigned short u16x8;
typedef __attribute__((ext_vector_type(4))) float f32x4;
typedef __attribute__((ext_vector_type(4))) unsigned int u32x4;

static __device__ __forceinline__ unsigned short f2bf(float x) {
    union { float f; unsigned u; } v; v.f = x;
    unsigned r = (v.u + 0x7FFFu + ((v.u >> 16) & 1u)) >> 16;  // RNE
    return (unsigned short)r;
}
static __device__ __forceinline__ float bf2f(unsigned short h) {
    union { unsigned u; float f; } v; v.u = ((unsigned)h) << 16;
    return v.f;
}
// bare hardware exp2 (v_exp_f32) — r33 win. Inputs bounded; denormal p~=0.
static __device__ __forceinline__ float fexp2(float x) {
#if __has_builtin(__builtin_amdgcn_exp2f)
    return __builtin_amdgcn_exp2f(x);
#else
    float r; asm("v_exp_f32 %0, %1" : "=v"(r) : "v"(x)); return r;
#endif
}

// packed f32x2 -> bf16x2 (v_cvt_pk_bf16_f32) as raw u32; low 16 = first arg
static __device__ __forceinline__ unsigned pk_bf16(float a, float b) {
    __hip_bfloat162 pk = __float22bfloat162_rn(make_float2(a, b));
    union { __hip_bfloat162 h; unsigned u; } v; v.h = pk;
    return v.u;
}

static __device__ __forceinline__ f32x4 mfma32(bf16x8 a, bf16x8 b, f32x4 c) {
    return __builtin_amdgcn_mfma_f32_16x16x32_bf16(a, b, c, 0, 0, 0);
}

// async global->LDS, 16B/lane; LDS dest = wave-uniform base + lane*16 (m97)
typedef __attribute__((address_space(3))) unsigned int lds_u32;
typedef __attribute__((address_space(1))) const unsigned int glb_u32;
static __device__ __forceinline__ void glds16(const unsigned short* g, unsigned short* l) {
    __builtin_amdgcn_global_load_lds((glb_u32*)g, (lds_u32*)l, 16, 0, 0);
}

// ---------------------------------------------------------------------------
// Merged prep: conv x->bf16 | transpose w_qkv | transpose w_proj.
// ---------------------------------------------------------------------------
#define PREP_CONV_ 1536   // 4096*768/(256*8)
#define PREP_TQKV_ 1728   // (2304/32)*(768/32)
#define PREP_TPRJ_ 576    // (768/32)*(768/32)
__global__ __launch_bounds__(256) void prep_kernel(
    const float* __restrict__ x,      unsigned short* __restrict__ x16,
    const float* __restrict__ w_qkv,  unsigned short* __restrict__ wqkvT,
    const float* __restrict__ w_proj, unsigned short* __restrict__ wprojT)
{
    __shared__ float tile[32][33];
    const int bid = blockIdx.x, t = threadIdx.x;
    if (bid < PREP_CONV_) {
        const int i = (bid * 256 + t) * 8;
        float4 a0 = *(const float4*)(x + i);
        float4 a1 = *(const float4*)(x + i + 4);
        u16x8 s;
        s[0] = f2bf(a0.x); s[1] = f2bf(a0.y); s[2] = f2bf(a0.z); s[3] = f2bf(a0.w);
        s[4] = f2bf(a1.x); s[5] = f2bf(a1.y); s[6] = f2bf(a1.z); s[7] = f2bf(a1.w);
        *(u16x8*)(x16 + i) = s;
        return;
    }
    const float* w; unsigned short* wT; int N, bb;
    if (bid < PREP_CONV_ + PREP_TQKV_) { w = w_qkv; wT = wqkvT; N = 3 * D_; bb = bid - PREP_CONV_; }
    else                               { w = w_proj; wT = wprojT; N = D_;   bb = bid - PREP_CONV_ - PREP_TQKV_; }
    const int K = D_;
    const int nt = N / 32;
    const int n0 = (bb % nt) * 32, k0 = (bb / nt) * 32;
    const int tx = t & 31, ty = t >> 5;
#pragma unroll
    for (int i = 0; i < 4; i++)
        tile[ty + i * 8][tx] = w[(size_t)(k0 + ty + i * 8) * N + n0 + tx];
    __syncthreads();
#pragma unroll
    for (int i = 0; i < 4; i++)
        wT[(size_t)(n0 + ty + i * 8) * K + k0 + tx] = f2bf(tile[tx][ty + i * 8]);
}

// ---------------------------------------------------------------------------
// GEMM1 (r30 structure + r35 XCD remap): BK=64 rows, XOR-swizzled g^(row&7),
// single-buffer. 1-D grid: xcd=id&7 owns MPX m-panels x NBX n-blocks ->
// L2-resident operand panels per XCD. VSPLIT epilogue (r31): V-region
// blocks write C transposed into vt[bh][hd][s].
// ---------------------------------------------------------------------------
template <int BM, int BN, int NBX, int MPX, bool OUT_F32, bool VSPLIT>
__global__ __launch_bounds__(256) void gemm_bt_kernel(
    const unsigned short* __restrict__ A,
    const unsigned short* __restrict__ Bt,
    const float* __restrict__ bias,
    void* __restrict__ Cp,
    unsigned short* __restrict__ vt,   // VSPLIT target (else unused)
    int M, int N, int K)
{
    constexpr int BK = 64;
    __shared__ __align__(16) unsigned short As[BM][BK];
    __shared__ __align__(16) unsigned short Bs[BN][BK];
    constexpr int MI = BM / 32, NJ = BN / 32;     // frags per wave quadrant
    constexpr int ACH = BM * BK / 8;              // 16B chunks per A tile
    constexpr int BCH = BN * BK / 8;

    const int t = threadIdx.x;
    const int w = t >> 6, lane = t & 63, quad = lane >> 4, l16 = lane & 15;
    // XCD-aware decode: xcd owns MPX contiguous m-panels (A L2-resident)
    const int id = blockIdx.x;
    const int xcd = id & 7, ix = id >> 3;
    const int m0 = (xcd * MPX + ix / NBX) * BM;
    const int n0 = (ix % NBX) * BN;
    const int mw = (w & 1) * (BM / 2), nw = (w >> 1) * (BN / 2);

    const f32x4 z = {0.f, 0.f, 0.f, 0.f};
    f32x4 acc[MI][NJ];
#pragma unroll
    for (int i = 0; i < MI; i++)
#pragma unroll
        for (int j = 0; j < NJ; j++) acc[i][j] = z;

    for (int kk = 0; kk < K; kk += BK) {
#pragma unroll
        for (int it = 0; it < ACH / 256; it++) {
            const int c = t + it * 256;
            const int row = c >> 3, gs = (c & 7) ^ (row & 7);
            glds16(A + (size_t)(m0 + row) * K + kk + gs * 8, &As[0][0] + c * 8);
        }
#pragma unroll
        for (int it = 0; it < BCH / 256; it++) {
            const int c = t + it * 256;
            const int row = c >> 3, gs = (c & 7) ^ (row & 7);
            glds16(Bt + (size_t)(n0 + row) * K + kk + gs * 8, &Bs[0][0] + c * 8);
        }
        __syncthreads();

#pragma unroll
        for (int k2 = 0; k2 < 2; k2++) {
            bf16x8 a[MI], b[NJ];
#pragma unroll
            for (int i = 0; i < MI; i++) {
                const int row = mw + i * 16 + l16;
                const int p = (quad + k2 * 4) ^ (row & 7);
                a[i] = *(const bf16x8*)(&As[row][p * 8]);
            }
#pragma unroll
            for (int j = 0; j < NJ; j++) {
                const int row = nw + j * 16 + l16;
                const int p = (quad + k2 * 4) ^ (row & 7);
                b[j] = *(const bf16x8*)(&Bs[row][p * 8]);
            }
#pragma unroll
            for (int i = 0; i < MI; i++)
#pragma unroll
                for (int j = 0; j < NJ; j++)
                    acc[i][j] = mfma32(a[i], b[j], acc[i][j]);
        }
        __syncthreads();
    }

    if (VSPLIT && n0 >= 2 * D_) {
        // V region: write transposed into vt[bh][hd][s], 4 consec s = 8B.
#pragma unroll
        for (int j = 0; j < NJ; j++) {
            const int gcol = n0 + nw + j * 16 + l16;
            const int col = gcol - 2 * D_;
            const int hh = col >> 6, hd = col & 63;
            const float bv = bias[gcol];
#pragma unroll
            for (int i = 0; i < MI; i++) {
                const int row = m0 + mw + i * 16 + quad * 4;
                const int bb = row >> 11, ss = row & 2047;
                unsigned long long pkv = 0;
#pragma unroll
                for (int r = 0; r < 4; r++)
                    pkv |= (unsigned long long)f2bf(acc[i][j][r] + bv) << (16 * r);
                *(unsigned long long*)(vt +
                    ((size_t)(bb * H_ + hh) * HD_ + hd) * S_ + ss) = pkv;
            }
        }
        return;
    }

#pragma unroll
    for (int j = 0; j < NJ; j++) {
        const int col = n0 + nw + j * 16 + l16;
        const float bv = bias[col];
#pragma unroll
        for (int i = 0; i < MI; i++) {
#pragma unroll
            for (int r = 0; r < 4; r++) {
                const int row = m0 + mw + i * 16 + quad * 4 + r;
                const float v = acc[i][j][r] + bv;
                if (OUT_F32) ((float*)Cp)[(size_t)row * N + col] = v;
                else         ((unsigned short*)Cp)[(size_t)row * N + col] = f2bf(v);
            }
        }
    }
}

// ---------------------------------------------------------------------------
// GEMM2 (r35): 64x64, BK=64, r34's 3-buffer counted-vmcnt pipeline.
// Per iter: stage tile kk+2 (4 glds16/thread), compute tile kk, wait
// vmcnt(4) (tile kk+1 landed, kk+2 in flight) + raw barrier. LDS 48KB;
// grid 768 already caps residency at 3 blk/CU -> no occupancy cost.
// XCD remap: xcd owns 8 m-panels x 12 n-blocks (~2MB = L2-resident).
// ---------------------------------------------------------------------------
__global__ __launch_bounds__(256) void gemm2_kernel(
    const unsigned short* __restrict__ A,    // o_x16 [4096][768]
    const unsigned short* __restrict__ Bt,   // wprojT [768][768]
    const float* __restrict__ bias,
    float* __restrict__ out)                 // [4096][768] f32
{
    __shared__ __align__(16) unsigned short As[3][64][64];
    __shared__ __align__(16) unsigned short Bs[3][64][64];

    const int t = threadIdx.x;
    const int w = t >> 6, lane = t & 63, quad = lane >> 4, l16 = lane & 15;
    const int id = blockIdx.x;
    const int xcd = id & 7, ix = id >> 3;
    const int m0 = (xcd * 8 + ix / 12) * 64;
    const int n0 = (ix % 12) * 64;
    const int mw = (w & 1) * 32, nw = (w >> 1) * 32;

    // per-thread staging addresses (pre-swizzled source, linear LDS dest)
    const int r0 = t >> 3, g0 = (t & 7) ^ (r0 & 7);
    const int c1 = t + 256, r1 = c1 >> 3, g1 = (c1 & 7) ^ (r1 & 7);
    const unsigned short* a0p = A + (size_t)(m0 + r0) * D_ + g0 * 8;
    const unsigned short* a1p = A + (size_t)(m0 + r1) * D_ + g1 * 8;
    const unsigned short* b0p = Bt + (size_t)(n0 + r0) * D_ + g0 * 8;
    const unsigned short* b1p = Bt + (size_t)(n0 + r1) * D_ + g1 * 8;

    auto stage = [&](int bi, int kk) {
        glds16(a0p + kk, &As[bi][0][0] + t * 8);
        glds16(a1p + kk, &As[bi][0][0] + (t + 256) * 8);
        glds16(b0p + kk, &Bs[bi][0][0] + t * 8);
        glds16(b1p + kk, &Bs[bi][0][0] + (t + 256) * 8);
    };

    const f32x4 z = {0.f, 0.f, 0.f, 0.f};
    f32x4 acc[2][2] = {{z, z}, {z, z}};

    // prologue: tiles 0,1 into bufs 0,1 (8 loads in flight/thread)
    stage(0, 0);
    stage(1, 64);
    asm volatile("s_waitcnt vmcnt(4)" ::: "memory");  // tile 0 landed
    __builtin_amdgcn_s_barrier();

    const int NK = D_ / 64;  // 12
    int bc = 0;
    for (int kk = 0; kk < NK; kk++) {
        const bool pre = (kk + 2 < NK);
        if (pre) {
            const int bp = (bc + 2 >= 3) ? bc - 1 : bc + 2;
            stage(bp, (kk + 2) * 64);
        }

#pragma unroll
        for (int k2 = 0; k2 < 2; k2++) {
            bf16x8 a[2], b[2];
#pragma unroll
            for (int i = 0; i < 2; i++) {
                const int row = mw + i * 16 + l16;
                const int p = (quad + k2 * 4) ^ (row & 7);
                a[i] = *(const bf16x8*)(&As[bc][row][p * 8]);
            }
#pragma unroll
            for (int j = 0; j < 2; j++) {
                const int row = nw + j * 16 + l16;
                const int p = (quad + k2 * 4) ^ (row & 7);
                b[j] = *(const bf16x8*)(&Bs[bc][row][p * 8]);
            }
#pragma unroll
            for (int i = 0; i < 2; i++)
#pragma unroll
                for (int j = 0; j < 2; j++)
                    acc[i][j] = mfma32(a[i], b[j], acc[i][j]);
        }

        if (pre) asm volatile("s_waitcnt vmcnt(4)" ::: "memory");
        else     asm volatile("s_waitcnt vmcnt(0)" ::: "memory");
        __builtin_amdgcn_s_barrier();
        bc = (bc + 1 == 3) ? 0 : bc + 1;
    }

#pragma unroll
    for (int j = 0; j < 2; j++) {
        const int col = n0 + nw + j * 16 + l16;
        const float bv = bias[col];
#pragma unroll
        for (int i = 0; i < 2; i++) {
#pragma unroll
            for (int r = 0; r < 4; r++) {
                const int row = m0 + mw + i * 16 + quad * 4 + r;
                out[(size_t)row * D_ + col] = acc[i][j][r] + bv;
            }
        }
    }
}

// ---------------------------------------------------------------------------
// Flash attention — r34 verbatim (45.2us): unsplit, XCD remap, raw v_exp,
// 3-buffer 2-deep counted-vmcnt pipeline (stage kt+2, wait vmcnt(4)).
//
// Key-row permutation (r22, verified): A-frag row l16 of tile-slice nt reads
// Ks row rowp = (nt>>1)*32 + (l16>>2)*8 + (nt&1)*4 + (l16&3) =>
// s_acc[nt][r] = S[key=(nt>>1)*32+quad*8+(nt&1)*4+r][q=l16]; packed pa0/pa1
// are exactly the PV A-frags. Ks swizzle sK(row)=(row&3)|((row>>3&1)<<2);
// Vs swizzle g^(row&7); glds16 with pre-swizzled global source.
// l-ones: mfma(pa, ones) -> C rows match o_acc rows; l[r] lane-local.
// ---------------------------------------------------------------------------
__global__ __launch_bounds__(256) void attn_kernel(
    const unsigned short* __restrict__ qkv,  // [B*S][3*D] bf16
    const unsigned short* __restrict__ vt,   // [B*H][HD][S] bf16
    unsigned short* __restrict__ o)          // [B*S][D] bf16
{
    __shared__ __align__(16) unsigned short Ks[3][64][64];   // [key][hd], sK swizzle
    __shared__ __align__(16) unsigned short Vs[3][64][64];   // [hd][key], g^(row&7)

    const int t = threadIdx.x;
    const int w = t >> 6, lane = t & 63, quad = lane >> 4, l16 = lane & 15;
    const int h8 = l16 & 7;
    // XCD-aware decode (bijective over 768 blocks; 8 XCDs round-robin)
    const int id = blockIdx.x;
    const int xcd = id & 7, ix = id >> 3;
    const int bh = xcd * 3 + (ix >> 5);      // 0..23
    const int qt = ix & 31;
    const int b = bh / H_, h = bh % H_;
    const int ld = 3 * D_;  // 2304

    // Q B-frags (n=l16 -> q row, k=quad*8+j), prescaled by SCALE*log2e
    const unsigned short* qbase =
        qkv + (size_t)(b * S_ + qt * 64 + 16 * w + l16) * ld + h * HD_;
    u16x8 qr0 = *(const u16x8*)(qbase + quad * 8);
    u16x8 qr1 = *(const u16x8*)(qbase + 32 + quad * 8);
    bf16x8 qf0, qf1;
#pragma unroll
    for (int j = 0; j < 8; j++) {
        qf0[j] = (short)f2bf(bf2f(qr0[j]) * EXP2C_);
        qf1[j] = (short)f2bf(bf2f(qr1[j]) * EXP2C_);
    }

    bf16x8 ones;
#pragma unroll
    for (int j = 0; j < 8; j++) ones[j] = (short)0x3F80;  // bf16 1.0

    const unsigned short* kbase = qkv + (size_t)(b * S_) * ld + D_ + h * HD_;
    const unsigned short* vbase = vt + (size_t)bh * HD_ * S_;

    // per-lane staging source addresses (pre-swizzled global groups)
    const int c0 = t, c1 = t + 256;
    const int row0 = c0 >> 3, row1 = c1 >> 3;
    const int kg0 = (c0 & 7) ^ ((row0 & 3) | (((row0 >> 3) & 1) << 2));
    const int kg1 = (c1 & 7) ^ ((row1 & 3) | (((row1 >> 3) & 1) << 2));
    const int vg0 = (c0 & 7) ^ (row0 & 7);
    const int vg1 = (c1 & 7) ^ (row1 & 7);
    const unsigned short* kp0 = kbase + (size_t)row0 * ld + kg0 * 8;
    const unsigned short* kp1 = kbase + (size_t)row1 * ld + kg1 * 8;
    const unsigned short* vp0 = vbase + (size_t)row0 * S_ + vg0 * 8;
    const unsigned short* vp1 = vbase + (size_t)row1 * S_ + vg1 * 8;
    const size_t KSTEP = (size_t)64 * ld;  // elements per KV tile (K side)

    const f32x4 z = {0.f, 0.f, 0.f, 0.f};
    f32x4 o_acc[4] = {z, z, z, z};
    f32x4 l_acc = z;

    // prologue: stage tiles 0 and 1 into bufs 0 and 1 (8 loads in flight)
#pragma unroll
    for (int pt = 0; pt < 2; pt++) {
        glds16(kp0, &Ks[pt][0][0] + c0 * 8);
        glds16(kp1, &Ks[pt][0][0] + c1 * 8);
        glds16(vp0, &Vs[pt][0][0] + c0 * 8);
        glds16(vp1, &Vs[pt][0][0] + c1 * 8);
        kp0 += KSTEP; kp1 += KSTEP; vp0 += 64; vp1 += 64;
    }
    asm volatile("s_waitcnt vmcnt(4)" ::: "memory");  // tile 0 landed
    __builtin_amdgcn_s_barrier();

    const int NT = S_ / 64;  // 32
    int bc = 0;              // buffer holding tile kt
    for (int kt = 0; kt < NT; kt++) {
        const bool pre = (kt + 2 < NT);

        // stage tile kt+2 into buf (bc+2)%3 (async; stays in flight past
        // this iter's barrier — only tile kt+1's loads are waited on)
        if (pre) {
            const int bp = (bc + 2 >= 3) ? bc - 1 : bc + 2;
            unsigned short* kd = &Ks[bp][0][0];
            unsigned short* vd = &Vs[bp][0][0];
            glds16(kp0, kd + c0 * 8);
            glds16(kp1, kd + c1 * 8);
            glds16(vp0, vd + c0 * 8);
            glds16(vp1, vd + c1 * 8);
            kp0 += KSTEP; kp1 += KSTEP; vp0 += 64; vp1 += 64;
        }

        // S^T = K . Q^T from LDS: s_acc[nt][r] = S[key=perm(nt,quad*4+r)][q=l16]
        f32x4 s_acc[4] = {z, z, z, z};
#pragma unroll
        for (int nt = 0; nt < 4; nt++) {
            const int rowp = ((nt >> 1) << 5) + ((l16 >> 2) << 3) + ((nt & 1) << 2) + (l16 & 3);
            const int skr = (rowp & 3) | (((rowp >> 3) & 1) << 2);
            const unsigned short* kr = &Ks[bc][rowp][0];
            bf16x8 k0 = *(const bf16x8*)(kr + (quad ^ skr) * 8);
            bf16x8 k1 = *(const bf16x8*)(kr + ((quad ^ skr) ^ 4) * 8);
            s_acc[nt] = mfma32(k0, qf0, s_acc[nt]);
            s_acc[nt] = mfma32(k1, qf1, s_acc[nt]);
        }

        // V-frag reads issued early; lgkm latency hides under exp2/pack
        bf16x8 vr0[4], vr1[4];
#pragma unroll
        for (int nt = 0; nt < 4; nt++) {
            const int row = nt * 16 + l16;
            vr0[nt] = *(const bf16x8*)(&Vs[bc][row][(quad ^ h8) * 8]);
            vr1[nt] = *(const bf16x8*)(&Vs[bc][row][((quad ^ h8) ^ 4) * 8]);
        }

        // p = exp2(s) via bare v_exp_f32; pack to PV A-frags in registers
        f32x4 pr[4];
#pragma unroll
        for (int nt = 0; nt < 4; nt++) {
#pragma unroll
            for (int r = 0; r < 4; r++) pr[nt][r] = fexp2(s_acc[nt][r]);
        }
        union { u32x4 u; bf16x8 h; } ca, cb;
        ca.u[0] = pk_bf16(pr[0][0], pr[0][1]);
        ca.u[1] = pk_bf16(pr[0][2], pr[0][3]);
        ca.u[2] = pk_bf16(pr[1][0], pr[1][1]);
        ca.u[3] = pk_bf16(pr[1][2], pr[1][3]);
        cb.u[0] = pk_bf16(pr[2][0], pr[2][1]);
        cb.u[1] = pk_bf16(pr[2][2], pr[2][3]);
        cb.u[2] = pk_bf16(pr[3][0], pr[3][1]);
        cb.u[3] = pk_bf16(pr[3][2], pr[3][3]);
        const bf16x8 pa0 = ca.h, pa1 = cb.h;

        // l on the MFMA pipe: C rows match o_acc rows, dup over cols
        l_acc = mfma32(pa0, ones, l_acc);
        l_acc = mfma32(pa1, ones, l_acc);

        // O += P . V from LDS (register V frags)
#pragma unroll
        for (int nt = 0; nt < 4; nt++) {
            o_acc[nt] = mfma32(pa0, vr0[nt], o_acc[nt]);
            o_acc[nt] = mfma32(pa1, vr1[nt], o_acc[nt]);
        }

        // counted vmcnt: require tile kt+1 landed; tile kt+2 stays in flight
        if (pre) asm volatile("s_waitcnt vmcnt(4)" ::: "memory");
        else     asm volatile("s_waitcnt vmcnt(0)" ::: "memory");
        __builtin_amdgcn_s_barrier();
        bc = (bc + 1 == 3) ? 0 : bc + 1;
    }

    // epilogue: l[r] lane-local (dup over l16); normalize + direct bf16 write
#pragma unroll
    for (int r = 0; r < 4; r++) {
        const float inv = 1.f / l_acc[r];
        const int row = b * S_ + qt * 64 + 16 * w + quad * 4 + r;
        unsigned short* ob = o + (size_t)row * D_ + h * HD_;
#pragma unroll
        for (int nt = 0; nt < 4; nt++)
            ob[nt * 16 + l16] = f2bf(o_acc[nt][r] * inv);
    }
}

// ---------------------------------------------------------------------------
extern "C" void kernel_launch(void* const* d_in, const int* in_sizes, int n_in,
                              void* d_out, int out_size, void* d_ws, size_t ws_size,
                              hipStream_t stream) {
    const float* x      = (const float*)d_in[0];  // [4096][768]
    const float* w_qkv  = (const float*)d_in[1];  // [768][2304]
    const float* b_qkv  = (const float*)d_in[2];  // [2304]
    const float* w_proj = (const float*)d_in[3];  // [768][768]
    const float* b_proj = (const float*)d_in[4];  // [768]
    float* out = (float*)d_out;                   // [4096][768]

    // ws carve (bf16 elements). x16 ALIASES o: GEMM1 consumes x16 before
    // attn writes o (same stream, sequential).
    unsigned short* qkv    = (unsigned short*)d_ws;                     // 9,437,184
    unsigned short* vtb    = qkv    + (size_t)(B_ * S_) * (3 * D_);     // 3,145,728
    unsigned short* o_x16  = vtb    + (size_t)(B_ * H_) * HD_ * S_;     // 3,145,728
    unsigned short* wqkvT  = o_x16  + (size_t)(B_ * S_) * D_;           // 1,769,472
    unsigned short* wprojT = wqkvT  + (size_t)D_ * (3 * D_);            //   589,824

    dim3 blk(256);
    prep_kernel<<<dim3(PREP_CONV_ + PREP_TQKV_ + PREP_TPRJ_), blk, 0, stream>>>(
        x, o_x16, w_qkv, wqkvT, w_proj, wprojT);
    gemm_bt_kernel<128, 96, 24, 4, false, true><<<dim3(768), blk, 0, stream>>>(
        o_x16, wqkvT, b_qkv, qkv, vtb, B_ * S_, 3 * D_, D_);
    attn_kernel<<<dim3((S_ / 64) * (B_ * H_)), blk, 0, stream>>>(qkv, vtb, o_x16);
    gemm2_kernel<<<dim3(768), blk, 0, stream>>>(o_x16, wprojT, b_proj, out);
}

// Round 15
// 149.283 us; speedup vs baseline: 1.0185x; 1.0185x over previous
//
#include <hip/hip_runtime.h>
#include <hip/hip_bf16.h>

// Problem: B=2, S=2048, D=768, H=12, HD=64. fp32 in/out, bf16 MFMA inside.
// r36 = r34 GEMMs (149.3 champion config; r35's GEMM XCD remap + G2 pipeline
// REVERTED: 152.0, net -2.7) + attn KEY-SPLIT ACROSS WAVES:
// LDS pipe was ~85% busy (73.7k cyc reads + 18k writes / 108k wall) because
// all 4 waves read IDENTICAL K/V frags. New wave (wq,wk) owns 32q x 32keys:
// K reads 8->4 (r22 permutation on 2 key-slices: rowL=(l16>>2)*8+nt*4+
// (l16&3), key=wk*32+quad*8+nt*4+r), V reads 8->4 (K=32 PV = wave's exact
// key half), MFMA count unchanged (8 QK + 2 l + 8 PV). Cross-wave partial
// sum (o,l) via retired Ks buffer at the end (intra-block, one barrier).
// Win ledger: r4 LDS staging+dbuf, r5 xor-swizzle, r18 GEMM1 128x96,
// r22 swapped-QK^T in-register P, r24 glds16 pre-swizzled staging +
// l-on-MFMA, r30 GEMM BK=64 swizzle, r31 XCD remap (attn) + repack fold,
// r32 unsplit attn, r33 raw v_exp_f32, r34 attn 3-buf counted vmcnt (45.2).
// Failure ledger (do not revisit): r7 mfma16, r8 wave-split, r11 32x32 MFMA,
// r12 attn BK=64, r9/r13/r14 math micro-opts, r16 GEMM1 64x128, r20 GEMM2
// dbuf-at-BK32, r23 2-wave/32q blocks, r25 V-direct-global mid-iter, r27
// V-reg prefetch post-PV, r28 gemm2-fused combine, r29 cross-block combine
// (tripwire FAIL), r30 attn setprio, r26/r31 split-k (combine tax),
// r35 GEMM XCD remap + G2 3-buf pipeline (+2.7us).
#define B_ 2
#define S_ 2048
#define D_ 768
#define H_ 12
#define HD_ 64
#define EXP2C_ 0.1803368801111244f  // SCALE * log2(e), folded into Q

typedef __attribute__((ext_vector_type(8))) short bf16x8;
typedef __attribute__((ext_vector_type(8))) unsigned short u16x8;
typedef __attribute__((ext_vector_type(4))) float f32x4;
typedef __attribute__((ext_vector_type(4))) unsigned int u32x4;

static __device__ __forceinline__ unsigned short f2bf(float x) {
    union { float f; unsigned u; } v; v.f = x;
    unsigned r = (v.u + 0x7FFFu + ((v.u >> 16) & 1u)) >> 16;  // RNE
    return (unsigned short)r;
}
static __device__ __forceinline__ float bf2f(unsigned short h) {
    union { unsigned u; float f; } v; v.u = ((unsigned)h) << 16;
    return v.f;
}
// bare hardware exp2 (v_exp_f32) — r33 win. Inputs bounded; denormal p~=0.
static __device__ __forceinline__ float fexp2(float x) {
#if __has_builtin(__builtin_amdgcn_exp2f)
    return __builtin_amdgcn_exp2f(x);
#else
    float r; asm("v_exp_f32 %0, %1" : "=v"(r) : "v"(x)); return r;
#endif
}

// packed f32x2 -> bf16x2 (v_cvt_pk_bf16_f32) as raw u32; low 16 = first arg
static __device__ __forceinline__ unsigned pk_bf16(float a, float b) {
    __hip_bfloat162 pk = __float22bfloat162_rn(make_float2(a, b));
    union { __hip_bfloat162 h; unsigned u; } v; v.h = pk;
    return v.u;
}

static __device__ __forceinline__ f32x4 mfma32(bf16x8 a, bf16x8 b, f32x4 c) {
    return __builtin_amdgcn_mfma_f32_16x16x32_bf16(a, b, c, 0, 0, 0);
}

// async global->LDS, 16B/lane; LDS dest = wave-uniform base + lane*16 (m97)
typedef __attribute__((address_space(3))) unsigned int lds_u32;
typedef __attribute__((address_space(1))) const unsigned int glb_u32;
static __device__ __forceinline__ void glds16(const unsigned short* g, unsigned short* l) {
    __builtin_amdgcn_global_load_lds((glb_u32*)g, (lds_u32*)l, 16, 0, 0);
}

// ---------------------------------------------------------------------------
// Merged prep: conv x->bf16 | transpose w_qkv | transpose w_proj.
// ---------------------------------------------------------------------------
#define PREP_CONV_ 1536   // 4096*768/(256*8)
#define PREP_TQKV_ 1728   // (2304/32)*(768/32)
#define PREP_TPRJ_ 576    // (768/32)*(768/32)
__global__ __launch_bounds__(256) void prep_kernel(
    const float* __restrict__ x,      unsigned short* __restrict__ x16,
    const float* __restrict__ w_qkv,  unsigned short* __restrict__ wqkvT,
    const float* __restrict__ w_proj, unsigned short* __restrict__ wprojT)
{
    __shared__ float tile[32][33];
    const int bid = blockIdx.x, t = threadIdx.x;
    if (bid < PREP_CONV_) {
        const int i = (bid * 256 + t) * 8;
        float4 a0 = *(const float4*)(x + i);
        float4 a1 = *(const float4*)(x + i + 4);
        u16x8 s;
        s[0] = f2bf(a0.x); s[1] = f2bf(a0.y); s[2] = f2bf(a0.z); s[3] = f2bf(a0.w);
        s[4] = f2bf(a1.x); s[5] = f2bf(a1.y); s[6] = f2bf(a1.z); s[7] = f2bf(a1.w);
        *(u16x8*)(x16 + i) = s;
        return;
    }
    const float* w; unsigned short* wT; int N, bb;
    if (bid < PREP_CONV_ + PREP_TQKV_) { w = w_qkv; wT = wqkvT; N = 3 * D_; bb = bid - PREP_CONV_; }
    else                               { w = w_proj; wT = wprojT; N = D_;   bb = bid - PREP_CONV_ - PREP_TQKV_; }
    const int K = D_;
    const int nt = N / 32;
    const int n0 = (bb % nt) * 32, k0 = (bb / nt) * 32;
    const int tx = t & 31, ty = t >> 5;
#pragma unroll
    for (int i = 0; i < 4; i++)
        tile[ty + i * 8][tx] = w[(size_t)(k0 + ty + i * 8) * N + n0 + tx];
    __syncthreads();
#pragma unroll
    for (int i = 0; i < 4; i++)
        wT[(size_t)(n0 + ty + i * 8) * K + k0 + tx] = f2bf(tile[tx][ty + i * 8]);
}

// ---------------------------------------------------------------------------
// Pure-bf16 GEMM + bias (r34 config): BK=64 rows, XOR-swizzled g^(row&7) on
// staging (pre-swizzled glds16 source, linear LDS dest) and frag reads
// ((quad+k2*4)^(row&7)) -> <=2-way (free). VSPLIT epilogue (r31): V-region
// blocks write C transposed into vt[bh][hd][s].
// ---------------------------------------------------------------------------
template <int BM, int BN, bool OUT_F32, bool VSPLIT>
__global__ __launch_bounds__(256) void gemm_bt_kernel(
    const unsigned short* __restrict__ A,
    const unsigned short* __restrict__ Bt,
    const float* __restrict__ bias,
    void* __restrict__ Cp,
    unsigned short* __restrict__ vt,   // VSPLIT target (else unused)
    int M, int N, int K)
{
    constexpr int BK = 64;
    __shared__ __align__(16) unsigned short As[BM][BK];
    __shared__ __align__(16) unsigned short Bs[BN][BK];
    constexpr int MI = BM / 32, NJ = BN / 32;     // frags per wave quadrant
    constexpr int ACH = BM * BK / 8;              // 16B chunks per A tile
    constexpr int BCH = BN * BK / 8;

    const int t = threadIdx.x;
    const int w = t >> 6, lane = t & 63, quad = lane >> 4, l16 = lane & 15;
    const int n0 = blockIdx.x * BN, m0 = blockIdx.y * BM;
    const int mw = (w & 1) * (BM / 2), nw = (w >> 1) * (BN / 2);

    const f32x4 z = {0.f, 0.f, 0.f, 0.f};
    f32x4 acc[MI][NJ];
#pragma unroll
    for (int i = 0; i < MI; i++)
#pragma unroll
        for (int j = 0; j < NJ; j++) acc[i][j] = z;

    for (int kk = 0; kk < K; kk += BK) {
#pragma unroll
        for (int it = 0; it < ACH / 256; it++) {
            const int c = t + it * 256;
            const int row = c >> 3, gs = (c & 7) ^ (row & 7);
            glds16(A + (size_t)(m0 + row) * K + kk + gs * 8, &As[0][0] + c * 8);
        }
#pragma unroll
        for (int it = 0; it < BCH / 256; it++) {
            const int c = t + it * 256;
            const int row = c >> 3, gs = (c & 7) ^ (row & 7);
            glds16(Bt + (size_t)(n0 + row) * K + kk + gs * 8, &Bs[0][0] + c * 8);
        }
        __syncthreads();

#pragma unroll
        for (int k2 = 0; k2 < 2; k2++) {
            bf16x8 a[MI], b[NJ];
#pragma unroll
            for (int i = 0; i < MI; i++) {
                const int row = mw + i * 16 + l16;
                const int p = (quad + k2 * 4) ^ (row & 7);
                a[i] = *(const bf16x8*)(&As[row][p * 8]);
            }
#pragma unroll
            for (int j = 0; j < NJ; j++) {
                const int row = nw + j * 16 + l16;
                const int p = (quad + k2 * 4) ^ (row & 7);
                b[j] = *(const bf16x8*)(&Bs[row][p * 8]);
            }
#pragma unroll
            for (int i = 0; i < MI; i++)
#pragma unroll
                for (int j = 0; j < NJ; j++)
                    acc[i][j] = mfma32(a[i], b[j], acc[i][j]);
        }
        __syncthreads();
    }

    if (VSPLIT && n0 >= 2 * D_) {
        // V region: write transposed into vt[bh][hd][s], 4 consec s = 8B.
#pragma unroll
        for (int j = 0; j < NJ; j++) {
            const int gcol = n0 + nw + j * 16 + l16;
            const int col = gcol - 2 * D_;
            const int hh = col >> 6, hd = col & 63;
            const float bv = bias[gcol];
#pragma unroll
            for (int i = 0; i < MI; i++) {
                const int row = m0 + mw + i * 16 + quad * 4;
                const int bb = row >> 11, ss = row & 2047;
                unsigned long long pkv = 0;
#pragma unroll
                for (int r = 0; r < 4; r++)
                    pkv |= (unsigned long long)f2bf(acc[i][j][r] + bv) << (16 * r);
                *(unsigned long long*)(vt +
                    ((size_t)(bb * H_ + hh) * HD_ + hd) * S_ + ss) = pkv;
            }
        }
        return;
    }

#pragma unroll
    for (int j = 0; j < NJ; j++) {
        const int col = n0 + nw + j * 16 + l16;
        const float bv = bias[col];
#pragma unroll
        for (int i = 0; i < MI; i++) {
#pragma unroll
            for (int r = 0; r < 4; r++) {
                const int row = m0 + mw + i * 16 + quad * 4 + r;
                const float v = acc[i][j][r] + bv;
                if (OUT_F32) ((float*)Cp)[(size_t)row * N + col] = v;
                else         ((unsigned short*)Cp)[(size_t)row * N + col] = f2bf(v);
            }
        }
    }
}

// ---------------------------------------------------------------------------
// Flash attention — r36: KEY-SPLIT ACROSS WAVES. Wave (wq=w&1, wk=w>>1)
// owns q rows [wq*32, wq*32+32) x keys [wk*32, wk*32+32) of each 64-key
// tile. Per wave-iter: 4 K b128 reads + 4 V b128 reads (was 16 total),
// 8 QK + 2 l + 8 PV MFMAs (unchanged). Keeps r34's 3-buffer counted-vmcnt
// pipeline, XCD remap, raw v_exp. End: wk=1 waves publish (o,l) partials
// via retired Ks LDS; wk=0 waves sum, normalize, write bf16 o.
//
// QK mapping (r22 algebra, 2 key-slices): A-frag row l16 of slice nt reads
// Ks row wk*32 + (l16>>2)*8 + nt*4 + (l16&3) => s_acc[nt][qs] reg r =
// S[key=wk*32+quad*8+nt*4+r][q=wq*32+qs*16+l16]; packed pa[qs] (j=nt*4+r
// order) is exactly the K=32 PV A-frag over the wave's 32 keys.
// Ks swizzle sK(row)=(row&3)|((row>>3&1)<<2) (wk*32 offset only touches
// bit5 -> skr unchanged); kh group = ((kh<<2)|quad)^skr. Vs swizzle
// g^(row&7); V B-frag group = ((wk<<2)|quad)^(row&7), one read per dg.
// l-ones: mfma(pa, ones) -> l[q] partial over wave's keys, rows = o rows.
// ---------------------------------------------------------------------------
__global__ __launch_bounds__(256) void attn_kernel(
    const unsigned short* __restrict__ qkv,  // [B*S][3*D] bf16
    const unsigned short* __restrict__ vt,   // [B*H][HD][S] bf16
    unsigned short* __restrict__ o)          // [B*S][D] bf16
{
    __shared__ __align__(16) unsigned short Ks[3][64][64];   // [key][hd], sK swizzle
    __shared__ __align__(16) unsigned short Vs[3][64][64];   // [hd][key], g^(row&7)

    const int t = threadIdx.x;
    const int w = t >> 6, lane = t & 63, quad = lane >> 4, l16 = lane & 15;
    const int wq = w & 1, wk = w >> 1;
    // XCD-aware decode (bijective over 768 blocks; 8 XCDs round-robin)
    const int id = blockIdx.x;
    const int xcd = id & 7, ix = id >> 3;
    const int bh = xcd * 3 + (ix >> 5);      // 0..23
    const int qt = ix & 31;
    const int b = bh / H_, h = bh % H_;
    const int ld = 3 * D_;  // 2304

    // Q B-frags: q = qt*64 + wq*32 + qs*16 + l16, k-half kh; prescaled.
    bf16x8 qf[2][2];
#pragma unroll
    for (int qs = 0; qs < 2; qs++) {
        const unsigned short* qb =
            qkv + (size_t)(b * S_ + qt * 64 + wq * 32 + qs * 16 + l16) * ld + h * HD_;
#pragma unroll
        for (int kh = 0; kh < 2; kh++) {
            u16x8 qr = *(const u16x8*)(qb + kh * 32 + quad * 8);
#pragma unroll
            for (int j = 0; j < 8; j++)
                qf[qs][kh][j] = (short)f2bf(bf2f(qr[j]) * EXP2C_);
        }
    }

    bf16x8 ones;
#pragma unroll
    for (int j = 0; j < 8; j++) ones[j] = (short)0x3F80;  // bf16 1.0

    const unsigned short* kbase = qkv + (size_t)(b * S_) * ld + D_ + h * HD_;
    const unsigned short* vbase = vt + (size_t)bh * HD_ * S_;

    // per-lane staging source addresses (pre-swizzled global groups)
    const int c0 = t, c1 = t + 256;
    const int row0 = c0 >> 3, row1 = c1 >> 3;
    const int kg0 = (c0 & 7) ^ ((row0 & 3) | (((row0 >> 3) & 1) << 2));
    const int kg1 = (c1 & 7) ^ ((row1 & 3) | (((row1 >> 3) & 1) << 2));
    const int vg0 = (c0 & 7) ^ (row0 & 7);
    const int vg1 = (c1 & 7) ^ (row1 & 7);
    const unsigned short* kp0 = kbase + (size_t)row0 * ld + kg0 * 8;
    const unsigned short* kp1 = kbase + (size_t)row1 * ld + kg1 * 8;
    const unsigned short* vp0 = vbase + (size_t)row0 * S_ + vg0 * 8;
    const unsigned short* vp1 = vbase + (size_t)row1 * S_ + vg1 * 8;
    const size_t KSTEP = (size_t)64 * ld;  // elements per KV tile (K side)

    const f32x4 z = {0.f, 0.f, 0.f, 0.f};
    f32x4 o_acc[2][4];   // [qs][dg]
#pragma unroll
    for (int qs = 0; qs < 2; qs++)
#pragma unroll
        for (int dg = 0; dg < 4; dg++) o_acc[qs][dg] = z;
    f32x4 l_acc[2] = {z, z};

    // prologue: stage tiles 0 and 1 into bufs 0 and 1 (8 loads in flight)
#pragma unroll
    for (int pt = 0; pt < 2; pt++) {
        glds16(kp0, &Ks[pt][0][0] + c0 * 8);
        glds16(kp1, &Ks[pt][0][0] + c1 * 8);
        glds16(vp0, &Vs[pt][0][0] + c0 * 8);
        glds16(vp1, &Vs[pt][0][0] + c1 * 8);
        kp0 += KSTEP; kp1 += KSTEP; vp0 += 64; vp1 += 64;
    }
    asm volatile("s_waitcnt vmcnt(4)" ::: "memory");  // tile 0 landed
    __builtin_amdgcn_s_barrier();

    const int NT = S_ / 64;  // 32
    int bc = 0;              // buffer holding tile kt
    for (int kt = 0; kt < NT; kt++) {
        const bool pre = (kt + 2 < NT);

        // stage tile kt+2 (async; in flight past this iter's barrier)
        if (pre) {
            const int bp = (bc + 2 >= 3) ? bc - 1 : bc + 2;
            unsigned short* kd = &Ks[bp][0][0];
            unsigned short* vd = &Vs[bp][0][0];
            glds16(kp0, kd + c0 * 8);
            glds16(kp1, kd + c1 * 8);
            glds16(vp0, vd + c0 * 8);
            glds16(vp1, vd + c1 * 8);
            kp0 += KSTEP; kp1 += KSTEP; vp0 += 64; vp1 += 64;
        }

        // K frags (4 reads) + QK: s_acc[nt][qs] over wave's 32 keys
        f32x4 s_acc[2][2];
        bf16x8 kf[2][2];
#pragma unroll
        for (int nt = 0; nt < 2; nt++) {
            const int rowL = ((l16 >> 2) << 3) + (nt << 2) + (l16 & 3);
            const int row = wk * 32 + rowL;
            const int skr = (row & 3) | (((row >> 3) & 1) << 2);
            const unsigned short* kr = &Ks[bc][row][0];
            kf[nt][0] = *(const bf16x8*)(kr + (quad ^ skr) * 8);
            kf[nt][1] = *(const bf16x8*)(kr + ((quad | 4) ^ skr) * 8);
        }
#pragma unroll
        for (int nt = 0; nt < 2; nt++)
#pragma unroll
            for (int qs = 0; qs < 2; qs++) {
                s_acc[nt][qs] = mfma32(kf[nt][0], qf[qs][0], z);
                s_acc[nt][qs] = mfma32(kf[nt][1], qf[qs][1], s_acc[nt][qs]);
            }

        // V frags (4 reads, one per d-group); latency hides under exp2/pack
        bf16x8 vr[4];
#pragma unroll
        for (int dg = 0; dg < 4; dg++) {
            const int row = dg * 16 + l16;
            vr[dg] = *(const bf16x8*)(&Vs[bc][row][(((wk << 2) | quad) ^ (row & 7)) * 8]);
        }

        // p = exp2(s); pack to K=32 PV A-frags (j = nt*4 + r order)
        f32x4 pr[2][2];
#pragma unroll
        for (int nt = 0; nt < 2; nt++)
#pragma unroll
            for (int qs = 0; qs < 2; qs++)
#pragma unroll
                for (int r = 0; r < 4; r++) pr[nt][qs][r] = fexp2(s_acc[nt][qs][r]);
        union { u32x4 u; bf16x8 h; } pku[2];
#pragma unroll
        for (int qs = 0; qs < 2; qs++) {
            pku[qs].u[0] = pk_bf16(pr[0][qs][0], pr[0][qs][1]);
            pku[qs].u[1] = pk_bf16(pr[0][qs][2], pr[0][qs][3]);
            pku[qs].u[2] = pk_bf16(pr[1][qs][0], pr[1][qs][1]);
            pku[qs].u[3] = pk_bf16(pr[1][qs][2], pr[1][qs][3]);
        }

        // l + O on the MFMA pipe (partials over this wave's 32 keys)
#pragma unroll
        for (int qs = 0; qs < 2; qs++) {
            l_acc[qs] = mfma32(pku[qs].h, ones, l_acc[qs]);
#pragma unroll
            for (int dg = 0; dg < 4; dg++)
                o_acc[qs][dg] = mfma32(pku[qs].h, vr[dg], o_acc[qs][dg]);
        }

        // counted vmcnt: tile kt+1 landed; tile kt+2 stays in flight
        if (pre) asm volatile("s_waitcnt vmcnt(4)" ::: "memory");
        else     asm volatile("s_waitcnt vmcnt(0)" ::: "memory");
        __builtin_amdgcn_s_barrier();
        bc = (bc + 1 == 3) ? 0 : bc + 1;
    }

    // ---- cross-wave reduction: wk=1 publishes partials via retired Ks ----
    float* oS = (float*)&Ks[0][0][0];   // [64 q][64 d] f32 = 16 KB
    float* lS = (float*)&Vs[0][0][0];   // [64 q] f32
    if (wk == 1) {
#pragma unroll
        for (int qs = 0; qs < 2; qs++) {
#pragma unroll
            for (int r = 0; r < 4; r++) {
                const int qloc = wq * 32 + qs * 16 + quad * 4 + r;
#pragma unroll
                for (int dg = 0; dg < 4; dg++)
                    oS[qloc * 64 + dg * 16 + l16] = o_acc[qs][dg][r];
                if (l16 == 0) lS[qloc] = l_acc[qs][r];
            }
        }
    }
    __syncthreads();
    if (wk == 0) {
#pragma unroll
        for (int qs = 0; qs < 2; qs++) {
#pragma unroll
            for (int r = 0; r < 4; r++) {
                const int qloc = wq * 32 + qs * 16 + quad * 4 + r;
                const float inv = 1.f / (l_acc[qs][r] + lS[qloc]);
                const int row = b * S_ + qt * 64 + qloc;
                unsigned short* ob = o + (size_t)row * D_ + h * HD_;
#pragma unroll
                for (int dg = 0; dg < 4; dg++)
                    ob[dg * 16 + l16] =
                        f2bf((o_acc[qs][dg][r] + oS[qloc * 64 + dg * 16 + l16]) * inv);
            }
        }
    }
}

// ---------------------------------------------------------------------------
extern "C" void kernel_launch(void* const* d_in, const int* in_sizes, int n_in,
                              void* d_out, int out_size, void* d_ws, size_t ws_size,
                              hipStream_t stream) {
    const float* x      = (const float*)d_in[0];  // [4096][768]
    const float* w_qkv  = (const float*)d_in[1];  // [768][2304]
    const float* b_qkv  = (const float*)d_in[2];  // [2304]
    const float* w_proj = (const float*)d_in[3];  // [768][768]
    const float* b_proj = (const float*)d_in[4];  // [768]
    float* out = (float*)d_out;                   // [4096][768]

    // ws carve (bf16 elements). x16 ALIASES o: GEMM1 consumes x16 before
    // attn writes o (same stream, sequential).
    unsigned short* qkv    = (unsigned short*)d_ws;                     // 9,437,184
    unsigned short* vtb    = qkv    + (size_t)(B_ * S_) * (3 * D_);     // 3,145,728
    unsigned short* o_x16  = vtb    + (size_t)(B_ * H_) * HD_ * S_;     // 3,145,728
    unsigned short* wqkvT  = o_x16  + (size_t)(B_ * S_) * D_;           // 1,769,472
    unsigned short* wprojT = wqkvT  + (size_t)D_ * (3 * D_);            //   589,824

    dim3 blk(256);
    prep_kernel<<<dim3(PREP_CONV_ + PREP_TQKV_ + PREP_TPRJ_), blk, 0, stream>>>(
        x, o_x16, w_qkv, wqkvT, w_proj, wprojT);
    gemm_bt_kernel<128, 96, false, true><<<dim3((3 * D_) / 96, (B_ * S_) / 128), blk, 0, stream>>>(
        o_x16, wqkvT, b_qkv, qkv, vtb, B_ * S_, 3 * D_, D_);
    attn_kernel<<<dim3((S_ / 64) * (B_ * H_)), blk, 0, stream>>>(qkv, vtb, o_x16);
    gemm_bt_kernel<64, 64, true, false><<<dim3(D_ / 64, (B_ * S_) / 64), blk, 0, stream>>>(
        o_x16, wprojT, b_proj, out, nullptr, B_ * S_, D_, D_);
}